// Round 10
// baseline (177.072 us; speedup 1.0000x reference)
//
#include <hip/hip_runtime.h>
#include <hip/hip_bf16.h>
#include <math.h>

// Problem constants (b=2, n=2048, dim=512, h=8, dh=64, f=256, chunk=128)
#define NB    2
#define NSEQ  2048
#define DIMM  512
#define NH    8
#define DHd   64
#define FF    256
#define CHK   128
#define NCHK  16
#define NBH   16   // NB*NH

typedef unsigned short ushort_t;
typedef __attribute__((ext_vector_type(8))) __bf16 bf16x8;
typedef __attribute__((ext_vector_type(4))) float floatx4;

__device__ __forceinline__ unsigned short f2bf(float x) {
    union { __hip_bfloat16 h; unsigned short u; } v;
    v.h = __float2bfloat16(x);
    return v.u;
}
__device__ __forceinline__ float bf2f(unsigned short u) {
    union { unsigned short u2[2]; float f; } v;
    v.u2[0] = 0; v.u2[1] = u;
    return v.f;
}
__device__ __forceinline__ unsigned enc_f(float x) {
    unsigned u = __float_as_uint(x);
    return (u & 0x80000000u) ? ~u : (u | 0x80000000u);
}
__device__ __forceinline__ float dec_f(unsigned e) {
    unsigned u = (e & 0x80000000u) ? (e & 0x7fffffffu) : ~e;
    return __uint_as_float(u);
}

__device__ __forceinline__ void gload16(const void* g, void* l) {
    __builtin_amdgcn_global_load_lds(
        (const __attribute__((address_space(1))) void*)g,
        (__attribute__((address_space(3))) void*)l, 16, 0, 0);
}

// frag read from a 64-k-step tile (8 granules/row, xor-swizzled)
__device__ __forceinline__ bf16x8 frag8(const ushort_t* lds, int row, int kb) {
    return *((const bf16x8*)lds + row * 8 + (kb ^ (row & 7)));
}
// frag read from a 128-k tile (16 granules/row)
__device__ __forceinline__ bf16x8 fragS(const ushort_t* lds, int row, int kb) {
    return *((const bf16x8*)lds + row * 16 + (kb ^ (row & 15)));
}

// =====================================================================
// prep: init mk_u + conv x->bf16 + conv proj->bf16(*dn) + transpose W's
// =====================================================================
__global__ __launch_bounds__(256)
void prep(const float* __restrict__ x, const float* __restrict__ proj,
          const float* __restrict__ W0, const float* __restrict__ W1,
          const float* __restrict__ W2, const float* __restrict__ W3,
          ushort_t* __restrict__ xb, ushort_t* __restrict__ projb,
          ushort_t* __restrict__ T0, ushort_t* __restrict__ T1,
          ushort_t* __restrict__ T2, ushort_t* __restrict__ T3,
          unsigned* __restrict__ mk_u)
{
    __shared__ float t[32][33];
    const int b = blockIdx.x, tid = threadIdx.x;
    if (b < 2048) {
        const int gid = b * 256 + tid;
        const float4 v = *(const float4*)(x + (size_t)gid * 4);
        union { ushort4 v4; unsigned short s[4]; } pk;
        pk.s[0] = f2bf(v.x); pk.s[1] = f2bf(v.y); pk.s[2] = f2bf(v.z); pk.s[3] = f2bf(v.w);
        ((ushort4*)xb)[gid] = pk.v4;
    } else if (b < 2064) {
        const int gid = (b - 2048) * 256 + tid;
        const float dn = 0.35355339059327379f;   // 64^-0.25 folded into proj
        const float4 v = *(const float4*)(proj + (size_t)gid * 4);
        union { ushort4 v4; unsigned short s[4]; } pk;
        pk.s[0] = f2bf(v.x * dn); pk.s[1] = f2bf(v.y * dn);
        pk.s[2] = f2bf(v.z * dn); pk.s[3] = f2bf(v.w * dn);
        ((ushort4*)projb)[gid] = pk.v4;
    } else if (b < 3088) {
        const int idx = b - 2064;                // 0..1023
        const int z = idx >> 8, rem = idx & 255;
        const int bx = rem & 15, by = rem >> 4;
        const float* W = (z == 0) ? W0 : (z == 1) ? W1 : (z == 2) ? W2 : W3;
        ushort_t* T = (z == 0) ? T0 : (z == 1) ? T1 : (z == 2) ? T2 : T3;
        const int x0 = bx * 32, y0 = by * 32;
        const int tx = tid & 31, ty = tid >> 5;  // 32 x 8
#pragma unroll
        for (int i = 0; i < 4; i++)
            t[ty + i * 8][tx] = W[(size_t)(y0 + ty + i * 8) * DIMM + x0 + tx];
        __syncthreads();
#pragma unroll
        for (int i = 0; i < 4; i++)
            T[(size_t)(x0 + ty + i * 8) * DIMM + y0 + tx] = f2bf(t[tx][ty + i * 8]);
    } else {
        if (tid < NBH) mk_u[tid] = 0u;
    }
}

// =====================================================================
// MFMA main loop: C[128x128] += A[128xK] * B[128xK]^T
// =====================================================================
__device__ __forceinline__ void mfma_mainloop(
    const ushort_t* __restrict__ AG, const ushort_t* __restrict__ BG,
    ushort_t* As, ushort_t* Bs, int ldA, int ldB, int K,
    floatx4 acc[4][4], int tid)
{
    const int lane = tid & 63, wid = tid >> 6;
    const int q = lane >> 4, c = lane & 15;
    const int wm = (wid >> 1) * 64, wn = (wid & 1) * 64;

    for (int k0 = 0; k0 < K; k0 += 64) {
#pragma unroll
        for (int t = 0; t < 4; t++) {
            const int g = t * 256 + tid, r = g >> 3, kb = (g & 7) ^ (r & 7);
            gload16(AG + (size_t)r * ldA + k0 + kb * 8, As + (size_t)g * 8);
        }
#pragma unroll
        for (int t = 0; t < 4; t++) {
            const int g = t * 256 + tid, r = g >> 3, kb = (g & 7) ^ (r & 7);
            gload16(BG + (size_t)r * ldB + k0 + kb * 8, Bs + (size_t)g * 8);
        }
        __syncthreads();
#pragma unroll
        for (int ks = 0; ks < 2; ks++) {
            bf16x8 af[4], bfr[4];
#pragma unroll
            for (int i = 0; i < 4; i++) {
                af[i]  = frag8(As, wm + i * 16 + c, ks * 4 + q);
                bfr[i] = frag8(Bs, wn + i * 16 + c, ks * 4 + q);
            }
#pragma unroll
            for (int i = 0; i < 4; i++)
#pragma unroll
                for (int j = 0; j < 4; j++)
                    acc[i][j] = __builtin_amdgcn_mfma_f32_16x16x32_bf16(
                        af[i], bfr[j], acc[i][j], 0, 0, 0);
        }
        __syncthreads();
    }
}

// =====================================================================
// QKV projection: z=0 -> qb, z=1 -> kb (+ fused key-feature max), z=2 -> vTb.
// =====================================================================
__global__ __launch_bounds__(256)
void gemm_qkv(const ushort_t* __restrict__ xb,
              const ushort_t* __restrict__ Wtq, const ushort_t* __restrict__ Wtk,
              const ushort_t* __restrict__ Wtv, const ushort_t* __restrict__ projb,
              ushort_t* __restrict__ qb, ushort_t* __restrict__ kb,
              ushort_t* __restrict__ vTb, unsigned* __restrict__ mk_u)
{
    __shared__ alignas(16) ushort_t SM[25600];   // staging As/Bs; tile[128][136]; PS proj half
    __shared__ float red[256];
    ushort_t* As = SM;
    ushort_t* Bs = SM + 8192;
    ushort_t* PS = SM + 17408;                   // 8192 ushorts: 128f x 64k proj half
    const int tid = threadIdx.x;
    const int n0 = blockIdx.x * 128, m0 = blockIdx.y * 128, z = blockIdx.z;
    const ushort_t* Bt = (z == 0) ? Wtq : ((z == 1) ? Wtk : Wtv);

    floatx4 zero = {0.f, 0.f, 0.f, 0.f};
    floatx4 acc[4][4];
#pragma unroll
    for (int i = 0; i < 4; i++)
#pragma unroll
        for (int j = 0; j < 4; j++) acc[i][j] = zero;

    mfma_mainloop(xb + (size_t)m0 * DIMM, Bt + (size_t)n0 * DIMM, As, Bs,
                  DIMM, DIMM, DIMM, acc, tid);

    const int lane = tid & 63, wid = tid >> 6;
    const int q = lane >> 4, cl = lane & 15;
    const int wm = (wid >> 1) * 64, wn = (wid & 1) * 64;

    // C tile -> LDS (stride 136: 16B-aligned rows)
#pragma unroll
    for (int i = 0; i < 4; i++)
#pragma unroll
        for (int j = 0; j < 4; j++) {
            const int col = wn + j * 16 + cl;
#pragma unroll
            for (int r = 0; r < 4; r++) {
                const int row = wm + i * 16 + q * 4 + r;
                SM[row * 136 + col] = f2bf(acc[i][j][r]);
            }
        }
    __syncthreads();

    if (z < 2) {
        ushort_t* ob = (z == 0) ? qb : kb;
        if (z == 1) {
#pragma unroll
            for (int t = 0; t < 4; t++) {
                const int g = t * 256 + tid, f = g >> 3, kbg = (g & 7) ^ (f & 7);
                gload16(projb + (size_t)f * 64 + kbg * 8, PS + (size_t)g * 8);
            }
        }
#pragma unroll
        for (int p = 0; p < 16; p++) {
            const int idx = p * 256 + tid;
            const int row = idx >> 5, c4 = idx & 31;
            ushort4 o = *(const ushort4*)&SM[row * 136 + c4 * 4];
            *(ushort4*)(ob + (size_t)(m0 + row) * DIMM + n0 + c4 * 4) = o;
        }
        if (z == 1) {
            const int bb = m0 >> 11;
            const int h0 = n0 >> 6;
            float mx[2] = {-3.0e38f, -3.0e38f};
#pragma unroll
            for (int half = 0; half < 2; half++) {
                __syncthreads();   // PS DMA drained; prior-half frag reads done
#pragma unroll
                for (int hh = 0; hh < 2; hh++) {
                    floatx4 a2[4][4];
#pragma unroll
                    for (int i = 0; i < 4; i++)
#pragma unroll
                        for (int j = 0; j < 4; j++) a2[i][j] = zero;
#pragma unroll
                    for (int ks = 0; ks < 2; ks++) {
                        bf16x8 af[4], bfr[4];
#pragma unroll
                        for (int i = 0; i < 4; i++)
                            af[i] = *(const bf16x8*)&SM[(wm + i * 16 + cl) * 136 + hh * 64 + (ks * 4 + q) * 8];
#pragma unroll
                        for (int j = 0; j < 4; j++)
                            bfr[j] = frag8(PS, wn + j * 16 + cl, ks * 4 + q);
#pragma unroll
                        for (int i = 0; i < 4; i++)
#pragma unroll
                            for (int j = 0; j < 4; j++)
                                a2[i][j] = __builtin_amdgcn_mfma_f32_16x16x32_bf16(
                                    af[i], bfr[j], a2[i][j], 0, 0, 0);
                    }
#pragma unroll
                    for (int i = 0; i < 4; i++)
#pragma unroll
                        for (int j = 0; j < 4; j++)
#pragma unroll
                            for (int r = 0; r < 4; r++) mx[hh] = fmaxf(mx[hh], a2[i][j][r]);
                }
                if (half == 0) {
                    __syncthreads();
#pragma unroll
                    for (int t = 0; t < 4; t++) {
                        const int g = t * 256 + tid, f = g >> 3, kbg = (g & 7) ^ (f & 7);
                        gload16(projb + (size_t)(128 + f) * 64 + kbg * 8, PS + (size_t)g * 8);
                    }
                }
            }
#pragma unroll
            for (int hh = 0; hh < 2; hh++) {
                __syncthreads();
                red[tid] = mx[hh];
                __syncthreads();
                for (int s = 128; s > 0; s >>= 1) {
                    if (tid < s) red[tid] = fmaxf(red[tid], red[tid + s]);
                    __syncthreads();
                }
                if (tid == 0) atomicMax(&mk_u[bb * NH + h0 + hh], enc_f(red[0]));
            }
        }
    } else {
        const int bb = m0 >> 11, nbase = m0 & 2047;
#pragma unroll
        for (int p = 0; p < 16; p++) {
            const int idx = p * 256 + tid;
            const int cl2 = idx >> 5, n4 = idx & 31;
            const int C = n0 + cl2;
            const int h = C >> 6, e = C & 63;
            union { ushort4 v4; unsigned short s[4]; } pk;
#pragma unroll
            for (int k = 0; k < 4; k++) pk.s[k] = SM[(n4 * 4 + k) * 136 + cl2];
            *(ushort4*)(vTb + (((size_t)(bb * NH + h) * 64 + e)) * NSEQ + nbase + n4 * 4) = pk.v4;
        }
    }
}

// ---------- output projection ----------
__global__ __launch_bounds__(256)
void gemm_out(const ushort_t* __restrict__ attnb, const ushort_t* __restrict__ Wto,
              float* __restrict__ out, const float* __restrict__ bias)
{
    __shared__ alignas(16) ushort_t As[8192];
    __shared__ alignas(16) ushort_t Bs[8192];
    const int tid = threadIdx.x;
    const int n0 = blockIdx.x * 128, m0 = blockIdx.y * 128;

    floatx4 zero = {0.f, 0.f, 0.f, 0.f};
    floatx4 acc[4][4];
#pragma unroll
    for (int i = 0; i < 4; i++)
#pragma unroll
        for (int j = 0; j < 4; j++) acc[i][j] = zero;

    mfma_mainloop(attnb + (size_t)m0 * DIMM, Wto + (size_t)n0 * DIMM, As, Bs,
                  DIMM, DIMM, DIMM, acc, tid);

    const int lane = tid & 63, wid = tid >> 6;
    const int q = lane >> 4, c = lane & 15;
    const int wm = (wid >> 1) * 64, wn = (wid & 1) * 64;
#pragma unroll
    for (int i = 0; i < 4; i++)
#pragma unroll
        for (int j = 0; j < 4; j++) {
            const int col = n0 + wn + j * 16 + c;
            const float bv = bias[col];
#pragma unroll
            for (int r = 0; r < 4; r++) {
                const int row = m0 + wm + i * 16 + q * 4 + r;
                out[(size_t)row * DIMM + col] = acc[i][j][r] + bv;
            }
        }
}

// =====================================================================
// featk: key features + exp -> Ksum + fused CTXT (m-tile == chunk).
// kfb surface eliminated — chunk_out recomputes kf locally.
// =====================================================================
__global__ __launch_bounds__(256)
void featk(const ushort_t* __restrict__ kb_, const ushort_t* __restrict__ projb,
           const unsigned* __restrict__ mk_u, const ushort_t* __restrict__ vTb,
           float* __restrict__ CTXT, float* __restrict__ Ksum)
{
    __shared__ alignas(16) ushort_t SM[24576];   // staging As(8192)+Bs(16384); reused
    __shared__ float dtmp[256];
    __shared__ float diag_l[128];
    __shared__ float colp[2][256];
    ushort_t* As = SM;
    ushort_t* Bs = SM + 8192;
    const int tid = threadIdx.x, lane = tid & 63, wid = tid >> 6;
    const int q = lane >> 4, cl = lane & 15;
    const int m0 = blockIdx.x * 128, h = blockIdx.y;
    const int bb = m0 >> 11, nloc = m0 & 2047;
    const int bh = bb * NH + h;
    const int cidx = nloc >> 7;
    const ushort_t* Aq = kb_ + (size_t)m0 * DIMM + h * 64;

    // diag[row] = sum(k^2)/16
    {
        const int row = tid >> 1, half = tid & 1;
        float s = 0.f;
        const ushort_t* p = Aq + (size_t)row * DIMM + half * 32;
#pragma unroll
        for (int d = 0; d < 32; d += 4) {
            ushort4 w = *(const ushort4*)(p + d);
            float a = bf2f(w.x), b2 = bf2f(w.y), c2 = bf2f(w.z), d2 = bf2f(w.w);
            s += a * a + b2 * b2 + c2 * c2 + d2 * d2;
        }
        dtmp[tid] = s;
    }
    __syncthreads();
    if (tid < 128) diag_l[tid] = (dtmp[2 * tid] + dtmp[2 * tid + 1]) * 0.0625f;

#pragma unroll
    for (int t = 0; t < 4; t++) {
        const int g = t * 256 + tid, r = g >> 3, kb = (g & 7) ^ (r & 7);
        gload16(Aq + (size_t)r * DIMM + kb * 8, As + (size_t)g * 8);
    }
#pragma unroll
    for (int t = 0; t < 8; t++) {
        const int g = t * 256 + tid, r = g >> 3, kb = (g & 7) ^ (r & 7);
        gload16(projb + (size_t)r * 64 + kb * 8, Bs + (size_t)g * 8);
    }
    __syncthreads();

    floatx4 zero = {0.f, 0.f, 0.f, 0.f};
    floatx4 acc[4][8];
#pragma unroll
    for (int i = 0; i < 4; i++)
#pragma unroll
        for (int j = 0; j < 8; j++) acc[i][j] = zero;
    const int wm = (wid >> 1) * 64, wn = (wid & 1) * 128;
#pragma unroll
    for (int ks = 0; ks < 2; ks++) {
        bf16x8 af[4], bfr[8];
#pragma unroll
        for (int i = 0; i < 4; i++) af[i] = frag8(As, wm + i * 16 + cl, ks * 4 + q);
#pragma unroll
        for (int j = 0; j < 8; j++) bfr[j] = frag8(Bs, wn + j * 16 + cl, ks * 4 + q);
#pragma unroll
        for (int i = 0; i < 4; i++)
#pragma unroll
            for (int j = 0; j < 8; j++)
                acc[i][j] = __builtin_amdgcn_mfma_f32_16x16x32_bf16(
                    af[i], bfr[j], acc[i][j], 0, 0, 0);
    }
    __syncthreads();   // frag ds_reads complete (SM reusable); diag visible

    const float mk = dec_f(mk_u[bh]);
#pragma unroll
    for (int i = 0; i < 4; i++)
#pragma unroll
        for (int r = 0; r < 4; r++) {
            const int row = wm + i * 16 + q * 4 + r;
            const float cc = diag_l[row] + mk;
#pragma unroll
            for (int j = 0; j < 8; j++)
                acc[i][j][r] = 0.0625f * (__expf(acc[i][j][r] - cc) + 1.0e-4f);
        }

    // column sums from registers (quad shuffles)
#pragma unroll
    for (int j = 0; j < 8; j++) {
        float s = 0.f;
#pragma unroll
        for (int i = 0; i < 4; i++)
            s += acc[i][j][0] + acc[i][j][1] + acc[i][j][2] + acc[i][j][3];
        s += __shfl_xor(s, 16);
        s += __shfl_xor(s, 32);
        if (q == 0) colp[wid >> 1][wn + j * 16 + cl] = s;
    }
    __syncthreads();   // colp visible
    Ksum[((size_t)bh * NCHK + cidx) * FF + tid] = colp[0][tid] + colp[1][tid];

    // fused ctx: CTXT[bh][cidx][e][f] = sum_n vT[e][n] * kf[n][f]
    ushort_t* Vs = SM;
    ushort_t* T  = SM + 8192;
    const ushort_t* Vg = vTb + ((size_t)bh * 64) * NSEQ + nloc;
#pragma unroll
    for (int t = 0; t < 4; t++) {
        const int g = t * 256 + tid, r = g >> 4, kb = (g & 15) ^ (r & 15);
        gload16(Vg + (size_t)r * NSEQ + kb * 8, Vs + (size_t)g * 8);
    }

    const size_t cbase = ((size_t)bh * NCHK + cidx) * 64;
#pragma unroll
    for (int fq = 0; fq < 4; fq++) {
        if ((wid & 1) == (fq >> 1)) {
#pragma unroll
            for (int jj = 0; jj < 4; jj++) {
                const int j = (fq & 1) * 4 + jj;
#pragma unroll
                for (int i = 0; i < 4; i++)
#pragma unroll
                    for (int r = 0; r < 4; r++) {
                        const int n = wm + i * 16 + q * 4 + r;
                        T[(jj * 16 + cl) * 136 + n] = f2bf(acc[i][j][r]);
                    }
            }
        }
        __syncthreads();   // T ready; (fq=0) also drains Vs DMA
        floatx4 accc[4];
#pragma unroll
        for (int jj = 0; jj < 4; jj++) accc[jj] = zero;
#pragma unroll
        for (int kt = 0; kt < 4; kt++) {
            const bf16x8 av = fragS(Vs, wid * 16 + cl, kt * 4 + q);
#pragma unroll
            for (int jj = 0; jj < 4; jj++) {
                const bf16x8 bv = *(const bf16x8*)(T + (jj * 16 + cl) * 136 + (kt * 4 + q) * 8);
                accc[jj] = __builtin_amdgcn_mfma_f32_16x16x32_bf16(av, bv, accc[jj], 0, 0, 0);
            }
        }
#pragma unroll
        for (int jj = 0; jj < 4; jj++) {
            const int f = fq * 64 + jj * 16 + cl;
#pragma unroll
            for (int r = 0; r < 4; r++) {
                const int e = wid * 16 + q * 4 + r;
                CTXT[(cbase + e) * FF + f] = accc[jj][r];
            }
        }
        __syncthreads();
    }
}

// ---------- merged exclusive prefixes: blocks [0,1024) S-path, [1024,1040) Z-path ----------
__global__ void prefix_zs(float* __restrict__ Ksum, float* __restrict__ Zout,
                          const float* __restrict__ CTXT, ushort_t* __restrict__ ctxp,
                          float* __restrict__ Sout)
{
    const int b = blockIdx.x;
    if (b < 1024) {
        const int idx = b * 256 + threadIdx.x;
        const int bh = idx >> 14, ef = idx & 16383;
        const int e = ef >> 8, f = ef & 255;
        float run = 0.f;
#pragma unroll
        for (int c = 0; c < NCHK; c++) {
            const size_t o = (((size_t)bh * NCHK + c) * 64 + e) * FF + f;
            const float t = CTXT[o];
            ctxp[o] = f2bf(run);
            run += t;
        }
        Sout[((size_t)bh * FF + f) * 64 + e] = run;   // S[b,h,f,e]
    } else {
        const int idx = (b - 1024) * 256 + threadIdx.x;
        const int bh = idx >> 8, f = idx & 255;
        float run = 0.f;
#pragma unroll
        for (int c = 0; c < NCHK; c++) {
            const size_t o = ((size_t)(bh * NCHK + c)) * FF + f;
            const float t = Ksum[o];
            Ksum[o] = run;
            run += t;
        }
        Zout[(size_t)bh * FF + f] = run;
    }
}

// =====================================================================
// chunk output, full MFMA. qf AND kf recomputed in-block (QF + KF in LDS);
// qfb/kfb global surfaces eliminated. Stage 1 runs entirely from LDS.
// SMX map (128 KB flat):
//   [0,16384)     proj staging -> KF slices 0,1 -> S (fragS) -> out-tile
//   [16384,24576) qb staging   -> KF slice 2    -> Vt / ctxp staging
//   [24576,32768) kb staging   -> KF slice 3
//   [32768,65536) QF slices 0..3
// =====================================================================
__global__ __launch_bounds__(256)
void chunk_out_mfma(const ushort_t* __restrict__ qb_, const ushort_t* __restrict__ kb_,
                    const ushort_t* __restrict__ projb, const ushort_t* __restrict__ vTb,
                    const float* __restrict__ Zex, const ushort_t* __restrict__ ctxp,
                    const unsigned* __restrict__ mk_u, ushort_t* __restrict__ attnb)
{
    __shared__ alignas(16) ushort_t SMX[65536];
    __shared__ float zeps[256];
    __shared__ float rows_part[2][128];
    __shared__ float denp[256];
    __shared__ float den_l[128];
    __shared__ float dtmp[256];
    __shared__ float diag_l[128];
    __shared__ float diagk_l[128];
    __shared__ float mx2[2][128];

    const int tid = threadIdx.x, lane = tid & 63, wid = tid >> 6;
    const int q = lane >> 4, cl = lane & 15;
    const int bh = blockIdx.x >> 4, c = blockIdx.x & 15;
    const int bb = bh >> 3, h = bh & 7;
    const int n0 = c * CHK;
    const ushort_t* Aq = qb_ + ((size_t)(bb * NSEQ + n0)) * DIMM + h * 64;
    const ushort_t* Ak = kb_ + ((size_t)(bb * NSEQ + n0)) * DIMM + h * 64;

    zeps[tid] = Zex[((size_t)bh * NCHK + c) * FF + tid] + 1.0e-6f;

    // ---- phase 0: stage qb/kb/proj; compute diag for both ----
#pragma unroll
    for (int t = 0; t < 4; t++) {
        const int g = t * 256 + tid, r = g >> 3, kb2 = (g & 7) ^ (r & 7);
        gload16(Aq + (size_t)r * DIMM + kb2 * 8, SMX + 16384 + (size_t)g * 8);
    }
#pragma unroll
    for (int t = 0; t < 4; t++) {
        const int g = t * 256 + tid, r = g >> 3, kb2 = (g & 7) ^ (r & 7);
        gload16(Ak + (size_t)r * DIMM + kb2 * 8, SMX + 24576 + (size_t)g * 8);
    }
#pragma unroll
    for (int t = 0; t < 8; t++) {
        const int g = t * 256 + tid, r = g >> 3, kb2 = (g & 7) ^ (r & 7);
        gload16(projb + (size_t)r * 64 + kb2 * 8, SMX + (size_t)g * 8);
    }
    {
        const int row = tid >> 1, half = tid & 1;
        float s = 0.f;
        const ushort_t* p = Aq + (size_t)row * DIMM + half * 32;
#pragma unroll
        for (int d = 0; d < 32; d += 4) {
            ushort4 w = *(const ushort4*)(p + d);
            float a = bf2f(w.x), b2 = bf2f(w.y), c2 = bf2f(w.z), d2 = bf2f(w.w);
            s += a * a + b2 * b2 + c2 * c2 + d2 * d2;
        }
        dtmp[tid] = s;
    }
    __syncthreads();
    if (tid < 128) diag_l[tid] = (dtmp[2 * tid] + dtmp[2 * tid + 1]) * 0.0625f;
    __syncthreads();
    {
        const int row = tid >> 1, half = tid & 1;
        float s = 0.f;
        const ushort_t* p = Ak + (size_t)row * DIMM + half * 32;
#pragma unroll
        for (int d = 0; d < 32; d += 4) {
            ushort4 w = *(const ushort4*)(p + d);
            float a = bf2f(w.x), b2 = bf2f(w.y), c2 = bf2f(w.z), d2 = bf2f(w.w);
            s += a * a + b2 * b2 + c2 * c2 + d2 * d2;
        }
        dtmp[tid] = s;
    }
    __syncthreads();
    if (tid < 128) diagk_l[tid] = (dtmp[2 * tid] + dtmp[2 * tid + 1]) * 0.0625f;
    __syncthreads();   // staging + diag all visible

    const float mk = dec_f(mk_u[bh]);
    floatx4 zero = {0.f, 0.f, 0.f, 0.f};
    const int wmF = (wid >> 1) * 64, wnF = (wid & 1) * 128;

    // ---- qf: MFMA, row-max, exp, write QF ----
    {
        floatx4 accq[4][8];
#pragma unroll
        for (int i = 0; i < 4; i++)
#pragma unroll
            for (int j = 0; j < 8; j++) accq[i][j] = zero;
#pragma unroll
        for (int ks = 0; ks < 2; ks++) {
            bf16x8 af[4], bfr[8];
#pragma unroll
            for (int i = 0; i < 4; i++) af[i] = frag8(SMX + 16384, wmF + i * 16 + cl, ks * 4 + q);
#pragma unroll
            for (int j = 0; j < 8; j++) bfr[j] = frag8(SMX, wnF + j * 16 + cl, ks * 4 + q);
#pragma unroll
            for (int i = 0; i < 4; i++)
#pragma unroll
                for (int j = 0; j < 8; j++)
                    accq[i][j] = __builtin_amdgcn_mfma_f32_16x16x32_bf16(
                        af[i], bfr[j], accq[i][j], 0, 0, 0);
        }
#pragma unroll
        for (int i = 0; i < 4; i++)
#pragma unroll
            for (int r = 0; r < 4; r++) {
                const int row = wmF + i * 16 + q * 4 + r;
                float mx = -3.0e38f;
#pragma unroll
                for (int j = 0; j < 8; j++) mx = fmaxf(mx, accq[i][j][r]);
                mx = fmaxf(mx, __shfl_xor(mx, 1)); mx = fmaxf(mx, __shfl_xor(mx, 2));
                mx = fmaxf(mx, __shfl_xor(mx, 4)); mx = fmaxf(mx, __shfl_xor(mx, 8));
                if (cl == 0) mx2[wid & 1][row] = mx;
            }
        __syncthreads();
#pragma unroll
        for (int i = 0; i < 4; i++)
#pragma unroll
            for (int r = 0; r < 4; r++) {
                const int row = wmF + i * 16 + q * 4 + r;
                const float cc = diag_l[row] + fmaxf(mx2[0][row], mx2[1][row]);
#pragma unroll
                for (int j = 0; j < 8; j++) {
                    const int col = wnF + j * 16 + cl;
                    const float v = 0.0625f * (__expf(accq[i][j][r] - cc) + 1.0e-4f);
                    const int s = col >> 6, fp = col & 63;
                    SMX[32768 + s * 8192 + ((size_t)row * 8 + ((fp >> 3) ^ (row & 7))) * 8 + (fp & 7)] = f2bf(v);
                }
            }
    }

    // ---- kf: MFMA (proj still intact), exp, write KF into staging region ----
    {
        floatx4 acck[4][8];
#pragma unroll
        for (int i = 0; i < 4; i++)
#pragma unroll
            for (int j = 0; j < 8; j++) acck[i][j] = zero;
#pragma unroll
        for (int ks = 0; ks < 2; ks++) {
            bf16x8 af[4], bfr[8];
#pragma unroll
            for (int i = 0; i < 4; i++) af[i] = frag8(SMX + 24576, wmF + i * 16 + cl, ks * 4 + q);
#pragma unroll
            for (int j = 0; j < 8; j++) bfr[j] = frag8(SMX, wnF + j * 16 + cl, ks * 4 + q);
#pragma unroll
            for (int i = 0; i < 4; i++)
#pragma unroll
                for (int j = 0; j < 8; j++)
                    acck[i][j] = __builtin_amdgcn_mfma_f32_16x16x32_bf16(
                        af[i], bfr[j], acck[i][j], 0, 0, 0);
        }
#pragma unroll
        for (int i = 0; i < 4; i++)
#pragma unroll
            for (int r = 0; r < 4; r++) {
                const int row = wmF + i * 16 + q * 4 + r;
                const float cc = diagk_l[row] + mk;
#pragma unroll
                for (int j = 0; j < 8; j++)
                    acck[i][j][r] = 0.0625f * (__expf(acck[i][j][r] - cc) + 1.0e-4f);
            }
        __syncthreads();   // ALL waves done reading proj/qb/kb regions
#pragma unroll
        for (int i = 0; i < 4; i++)
#pragma unroll
            for (int r = 0; r < 4; r++) {
                const int row = wmF + i * 16 + q * 4 + r;
#pragma unroll
                for (int j = 0; j < 8; j++) {
                    const int col = wnF + j * 16 + cl;
                    const int s = col >> 6, fp = col & 63;
                    SMX[s * 8192 + ((size_t)row * 8 + ((fp >> 3) ^ (row & 7))) * 8 + (fp & 7)] = f2bf(acck[i][j][r]);
                }
            }
    }
    __syncthreads();   // QF + KF complete

    // ---- stage 1: S = Q @ Kf^T (K=256), entirely from LDS ----
    floatx4 acc1[4][4];
#pragma unroll
    for (int i = 0; i < 4; i++)
#pragma unroll
        for (int j = 0; j < 4; j++) acc1[i][j] = zero;
    const int wm = (wid >> 1) * 64, wn = (wid & 1) * 64;
#pragma unroll
    for (int s = 0; s < 4; s++) {
        const ushort_t* QFs = SMX + 32768 + s * 8192;
        const ushort_t* KFs = SMX + s * 8192;
#pragma unroll
        for (int ks = 0; ks < 2; ks++) {
            bf16x8 af[4], bfr[4];
#pragma unroll
            for (int i = 0; i < 4; i++) {
                af[i]  = frag8(QFs, wm + i * 16 + cl, ks * 4 + q);
                bfr[i] = frag8(KFs, wn + i * 16 + cl, ks * 4 + q);
            }
#pragma unroll
            for (int i = 0; i < 4; i++)
#pragma unroll
                for (int j = 0; j < 4; j++)
                    acc1[i][j] = __builtin_amdgcn_mfma_f32_16x16x32_bf16(
                        af[i], bfr[j], acc1[i][j], 0, 0, 0);
        }
    }
    __syncthreads();   // all KF reads done before S overwrites slices 0-1

    // ---- causal mask + rowsum(fp32) + S -> SMX[0..16384) (bf16, fragS) ----
#pragma unroll
    for (int i = 0; i < 4; i++)
#pragma unroll
        for (int r = 0; r < 4; r++) {
            const int row = wm + i * 16 + q * 4 + r;
            float part = 0.f;
#pragma unroll
            for (int j = 0; j < 4; j++) {
                const int col = wn + j * 16 + cl;
                const float v = (col <= row) ? acc1[i][j][r] : 0.f;
                part += v;
                SMX[((size_t)row * 16 + ((col >> 3) ^ (row & 15))) * 8 + (col & 7)] = f2bf(v);
            }
            part += __shfl_xor(part, 1); part += __shfl_xor(part, 2);
            part += __shfl_xor(part, 4); part += __shfl_xor(part, 8);
            if (cl == 0) rows_part[wid & 1][row] = part;
        }
    __syncthreads();

    // ---- stage 3: acc2[e][row] += vT (x) S  (K = 128 seq) ----
    floatx4 acc2[4][2];
#pragma unroll
    for (int i = 0; i < 4; i++)
#pragma unroll
        for (int j = 0; j < 2; j++) acc2[i][j] = zero;
    const ushort_t* Vt = vTb + ((size_t)bh * 64) * NSEQ + n0;
    for (int k0 = 0; k0 < CHK; k0 += 64) {
#pragma unroll
        for (int t = 0; t < 2; t++) {
            const int g = t * 256 + tid, r = g >> 3, kb2 = (g & 7) ^ (r & 7);
            gload16(Vt + (size_t)r * NSEQ + k0 + kb2 * 8, SMX + 16384 + (size_t)g * 8);
        }
        __syncthreads();
#pragma unroll
        for (int ks = 0; ks < 2; ks++) {
            bf16x8 af[4], bfr[2];
            const int kbS = (k0 >> 3) + ks * 4 + q;
#pragma unroll
            for (int i = 0; i < 4; i++) af[i] = frag8(SMX + 16384, i * 16 + cl, ks * 4 + q);
#pragma unroll
            for (int j = 0; j < 2; j++) bfr[j] = fragS(SMX, wid * 32 + j * 16 + cl, kbS);
#pragma unroll
            for (int i = 0; i < 4; i++)
#pragma unroll
                for (int j = 0; j < 2; j++)
                    acc2[i][j] = __builtin_amdgcn_mfma_f32_16x16x32_bf16(
                        af[i], bfr[j], acc2[i][j], 0, 0, 0);
        }
        __syncthreads();
    }

    // ---- stage 4: acc2 += ctxp (x) Q  (K = 256 features); Q/den from QF ----
    const ushort_t* Cp = ctxp + ((size_t)bh * NCHK + c) * 64 * FF;
    float dacc = 0.f;
    const int drow = tid & 127, dhalf = tid >> 7;
    for (int k0 = 0; k0 < FF; k0 += 64) {
#pragma unroll
        for (int t = 0; t < 2; t++) {
            const int g = t * 256 + tid, r = g >> 3, kb2 = (g & 7) ^ (r & 7);
            gload16(Cp + (size_t)r * FF + k0 + kb2 * 8, SMX + 16384 + (size_t)g * 8);
        }
        __syncthreads();
        const ushort_t* QFs = SMX + 32768 + (k0 >> 6) * 8192;
#pragma unroll
        for (int ks = 0; ks < 2; ks++) {
            bf16x8 af[4], bfr[2];
#pragma unroll
            for (int i = 0; i < 4; i++) af[i] = frag8(SMX + 16384, i * 16 + cl, ks * 4 + q);
#pragma unroll
            for (int j = 0; j < 2; j++) bfr[j] = frag8(QFs, wid * 32 + j * 16 + cl, ks * 4 + q);
#pragma unroll
            for (int i = 0; i < 4; i++)
#pragma unroll
                for (int j = 0; j < 2; j++)
                    acc2[i][j] = __builtin_amdgcn_mfma_f32_16x16x32_bf16(
                        af[i], bfr[j], acc2[i][j], 0, 0, 0);
        }
        // den partial: this thread's row, its 32-feature half of this k-step
#pragma unroll
        for (int gi = 0; gi < 4; gi++) {
            const int kb2 = dhalf * 4 + gi;
            const ushort_t* gp = QFs + ((size_t)drow * 8 + (kb2 ^ (drow & 7))) * 8;
            const int kbase = k0 + kb2 * 8;
#pragma unroll
            for (int e2 = 0; e2 < 8; e2++)
                dacc = fmaf(bf2f(gp[e2]), zeps[kbase + e2], dacc);
        }
        __syncthreads();
    }
    denp[tid] = dacc;
    __syncthreads();
    if (tid < 128)
        den_l[tid] = rows_part[0][tid] + rows_part[1][tid] + denp[tid] + denp[tid + 128];
    __syncthreads();

    // ---- epilogue: divide, transpose via LDS, coalesced bf16 store ----
#pragma unroll
    for (int j = 0; j < 2; j++) {
        const int row = wid * 32 + j * 16 + cl;
        const float dinv = 1.0f / den_l[row];
#pragma unroll
        for (int i = 0; i < 4; i++)
#pragma unroll
            for (int r = 0; r < 4; r++) {
                const int e = i * 16 + q * 4 + r;
                SMX[row * 68 + e] = f2bf(acc2[i][j][r] * dinv);
            }
    }
    __syncthreads();
#pragma unroll
    for (int p = 0; p < 8; p++) {
        const int idx = p * 256 + tid;
        const int row = idx >> 4, e4 = idx & 15;
        ushort4 o = *(const ushort4*)&SMX[row * 68 + e4 * 4];
        *(ushort4*)(attnb + ((size_t)(bb * NSEQ + n0 + row)) * DIMM + h * 64 + e4 * 4) = o;
    }
}

extern "C" void kernel_launch(void* const* d_in, const int* in_sizes, int n_in,
                              void* d_out, int out_size, void* d_ws, size_t ws_size,
                              hipStream_t stream)
{
    (void)in_sizes; (void)n_in; (void)out_size; (void)ws_size;
    const float* x    = (const float*)d_in[0];
    const float* proj = (const float*)d_in[1];
    const float* Wq   = (const float*)d_in[2];
    const float* Wk   = (const float*)d_in[3];
    const float* Wv   = (const float*)d_in[4];
    const float* Wo   = (const float*)d_in[5];
    const float* bo   = (const float*)d_in[6];
    float* out = (float*)d_out;

    // ---- workspace carve (~45 MB) ----
    char* W = (char*)d_ws;
    float*    CTXT = (float*)W;              W += (size_t)16777216;   // [bh][c][e][f] fp32
    ushort_t* ctxp = (ushort_t*)W;           W += (size_t)8388608;    // [bh][c][e][f] bf16
    ushort_t* qb   = (ushort_t*)W;           W += (size_t)4194304;    // [n][dim] bf16 (live into chunk_out)
    ushort_t* kb   = (ushort_t*)W;           W += (size_t)4194304;    // (live into chunk_out)
    ushort_t* xb   = (ushort_t*)W;           W += (size_t)4194304;    // reused as attnb
    ushort_t* vTb  = (ushort_t*)W;           W += (size_t)4194304;    // [bh][e][n]
    ushort_t* Wtq  = (ushort_t*)W;           W += (size_t)524288;
    ushort_t* Wtk  = (ushort_t*)W;           W += (size_t)524288;
    ushort_t* Wtv  = (ushort_t*)W;           W += (size_t)524288;
    ushort_t* Wto  = (ushort_t*)W;           W += (size_t)524288;
    ushort_t* projb = (ushort_t*)W;          W += (size_t)32768;
    float*    Ksum = (float*)W;              W += (size_t)262144;     // [bh][c][f]
    unsigned* mk_u = (unsigned*)W;           W += (size_t)256;

    ushort_t* attnb = xb;          // xb dead after gemm_qkv

    float* Zout = out + (size_t)4096 * 512;
    float* Sout = Zout + (size_t)NBH * FF;

    hipLaunchKernelGGL(prep, dim3(3089), dim3(256), 0, stream,
                       x, proj, Wq, Wk, Wv, Wo, xb, projb, Wtq, Wtk, Wtv, Wto, mk_u);
    hipLaunchKernelGGL(gemm_qkv, dim3(4, 32, 3), dim3(256), 0, stream,
                       xb, Wtq, Wtk, Wtv, projb, qb, kb, vTb, mk_u);
    hipLaunchKernelGGL(featk, dim3(32, 8), dim3(256), 0, stream,
                       kb, projb, mk_u, vTb, CTXT, Ksum);
    hipLaunchKernelGGL(prefix_zs, dim3(1040), dim3(256), 0, stream,
                       Ksum, Zout, CTXT, ctxp, Sout);
    hipLaunchKernelGGL(chunk_out_mfma, dim3(256), dim3(256), 0, stream,
                       qb, kb, projb, vTb, Ksum, ctxp, mk_u, attnb);
    hipLaunchKernelGGL(gemm_out, dim3(4, 32), dim3(256), 0, stream, attnb, Wto, out, bo);
}

// Round 11
// 149.788 us; speedup vs baseline: 1.1822x; 1.1822x over previous
//
#include <hip/hip_runtime.h>
#include <hip/hip_bf16.h>
#include <math.h>

// Problem constants (b=2, n=2048, dim=512, h=8, dh=64, f=256, chunk=128)
#define NB    2
#define NSEQ  2048
#define DIMM  512
#define NH    8
#define DHd   64
#define FF    256
#define CHK   128
#define NCHK  16
#define NBH   16   // NB*NH

typedef unsigned short ushort_t;
typedef __attribute__((ext_vector_type(8))) __bf16 bf16x8;
typedef __attribute__((ext_vector_type(4))) float floatx4;

__device__ __forceinline__ unsigned short f2bf(float x) {
    union { __hip_bfloat16 h; unsigned short u; } v;
    v.h = __float2bfloat16(x);
    return v.u;
}
__device__ __forceinline__ float bf2f(unsigned short u) {
    union { unsigned short u2[2]; float f; } v;
    v.u2[0] = 0; v.u2[1] = u;
    return v.f;
}
__device__ __forceinline__ unsigned enc_f(float x) {
    unsigned u = __float_as_uint(x);
    return (u & 0x80000000u) ? ~u : (u | 0x80000000u);
}
__device__ __forceinline__ float dec_f(unsigned e) {
    unsigned u = (e & 0x80000000u) ? (e & 0x7fffffffu) : ~e;
    return __uint_as_float(u);
}

__device__ __forceinline__ void gload16(const void* g, void* l) {
    __builtin_amdgcn_global_load_lds(
        (const __attribute__((address_space(1))) void*)g,
        (__attribute__((address_space(3))) void*)l, 16, 0, 0);
}

// frag read from a 64-k-step tile (8 granules/row, xor-swizzled)
__device__ __forceinline__ bf16x8 frag8(const ushort_t* lds, int row, int kb) {
    return *((const bf16x8*)lds + row * 8 + (kb ^ (row & 7)));
}
// frag read from a 128-k tile (16 granules/row)
__device__ __forceinline__ bf16x8 fragS(const ushort_t* lds, int row, int kb) {
    return *((const bf16x8*)lds + row * 16 + (kb ^ (row & 15)));
}

// =====================================================================
// prep: init mk_u + conv x->bf16 + conv proj->bf16(*dn) + transpose W's
// =====================================================================
__global__ __launch_bounds__(256)
void prep(const float* __restrict__ x, const float* __restrict__ proj,
          const float* __restrict__ W0, const float* __restrict__ W1,
          const float* __restrict__ W2, const float* __restrict__ W3,
          ushort_t* __restrict__ xb, ushort_t* __restrict__ projb,
          ushort_t* __restrict__ T0, ushort_t* __restrict__ T1,
          ushort_t* __restrict__ T2, ushort_t* __restrict__ T3,
          unsigned* __restrict__ mk_u)
{
    __shared__ float t[32][33];
    const int b = blockIdx.x, tid = threadIdx.x;
    if (b < 2048) {
        const int gid = b * 256 + tid;
        const float4 v = *(const float4*)(x + (size_t)gid * 4);
        union { ushort4 v4; unsigned short s[4]; } pk;
        pk.s[0] = f2bf(v.x); pk.s[1] = f2bf(v.y); pk.s[2] = f2bf(v.z); pk.s[3] = f2bf(v.w);
        ((ushort4*)xb)[gid] = pk.v4;
    } else if (b < 2064) {
        const int gid = (b - 2048) * 256 + tid;
        const float dn = 0.35355339059327379f;   // 64^-0.25 folded into proj
        const float4 v = *(const float4*)(proj + (size_t)gid * 4);
        union { ushort4 v4; unsigned short s[4]; } pk;
        pk.s[0] = f2bf(v.x * dn); pk.s[1] = f2bf(v.y * dn);
        pk.s[2] = f2bf(v.z * dn); pk.s[3] = f2bf(v.w * dn);
        ((ushort4*)projb)[gid] = pk.v4;
    } else if (b < 3088) {
        const int idx = b - 2064;                // 0..1023
        const int z = idx >> 8, rem = idx & 255;
        const int bx = rem & 15, by = rem >> 4;
        const float* W = (z == 0) ? W0 : (z == 1) ? W1 : (z == 2) ? W2 : W3;
        ushort_t* T = (z == 0) ? T0 : (z == 1) ? T1 : (z == 2) ? T2 : T3;
        const int x0 = bx * 32, y0 = by * 32;
        const int tx = tid & 31, ty = tid >> 5;  // 32 x 8
#pragma unroll
        for (int i = 0; i < 4; i++)
            t[ty + i * 8][tx] = W[(size_t)(y0 + ty + i * 8) * DIMM + x0 + tx];
        __syncthreads();
#pragma unroll
        for (int i = 0; i < 4; i++)
            T[(size_t)(x0 + ty + i * 8) * DIMM + y0 + tx] = f2bf(t[tx][ty + i * 8]);
    } else {
        if (tid < NBH) mk_u[tid] = 0u;
    }
}

// =====================================================================
// MFMA main loop: C[128x128] += A[128xK] * B[128xK]^T
// =====================================================================
__device__ __forceinline__ void mfma_mainloop(
    const ushort_t* __restrict__ AG, const ushort_t* __restrict__ BG,
    ushort_t* As, ushort_t* Bs, int ldA, int ldB, int K,
    floatx4 acc[4][4], int tid)
{
    const int lane = tid & 63, wid = tid >> 6;
    const int q = lane >> 4, c = lane & 15;
    const int wm = (wid >> 1) * 64, wn = (wid & 1) * 64;

    for (int k0 = 0; k0 < K; k0 += 64) {
#pragma unroll
        for (int t = 0; t < 4; t++) {
            const int g = t * 256 + tid, r = g >> 3, kb = (g & 7) ^ (r & 7);
            gload16(AG + (size_t)r * ldA + k0 + kb * 8, As + (size_t)g * 8);
        }
#pragma unroll
        for (int t = 0; t < 4; t++) {
            const int g = t * 256 + tid, r = g >> 3, kb = (g & 7) ^ (r & 7);
            gload16(BG + (size_t)r * ldB + k0 + kb * 8, Bs + (size_t)g * 8);
        }
        __syncthreads();
#pragma unroll
        for (int ks = 0; ks < 2; ks++) {
            bf16x8 af[4], bfr[4];
#pragma unroll
            for (int i = 0; i < 4; i++) {
                af[i]  = frag8(As, wm + i * 16 + c, ks * 4 + q);
                bfr[i] = frag8(Bs, wn + i * 16 + c, ks * 4 + q);
            }
#pragma unroll
            for (int i = 0; i < 4; i++)
#pragma unroll
                for (int j = 0; j < 4; j++)
                    acc[i][j] = __builtin_amdgcn_mfma_f32_16x16x32_bf16(
                        af[i], bfr[j], acc[i][j], 0, 0, 0);
        }
        __syncthreads();
    }
}

// =====================================================================
// QKV projection: z=0 -> qb, z=1 -> kb (+ fused key-feature max), z=2 -> vTb.
// =====================================================================
__global__ __launch_bounds__(256)
void gemm_qkv(const ushort_t* __restrict__ xb,
              const ushort_t* __restrict__ Wtq, const ushort_t* __restrict__ Wtk,
              const ushort_t* __restrict__ Wtv, const ushort_t* __restrict__ projb,
              ushort_t* __restrict__ qb, ushort_t* __restrict__ kb,
              ushort_t* __restrict__ vTb, unsigned* __restrict__ mk_u)
{
    __shared__ alignas(16) ushort_t SM[25600];   // staging As/Bs; tile[128][136]; PS proj half
    __shared__ float red[256];
    ushort_t* As = SM;
    ushort_t* Bs = SM + 8192;
    ushort_t* PS = SM + 17408;                   // 8192 ushorts: 128f x 64k proj half
    const int tid = threadIdx.x;
    const int n0 = blockIdx.x * 128, m0 = blockIdx.y * 128, z = blockIdx.z;
    const ushort_t* Bt = (z == 0) ? Wtq : ((z == 1) ? Wtk : Wtv);

    floatx4 zero = {0.f, 0.f, 0.f, 0.f};
    floatx4 acc[4][4];
#pragma unroll
    for (int i = 0; i < 4; i++)
#pragma unroll
        for (int j = 0; j < 4; j++) acc[i][j] = zero;

    mfma_mainloop(xb + (size_t)m0 * DIMM, Bt + (size_t)n0 * DIMM, As, Bs,
                  DIMM, DIMM, DIMM, acc, tid);

    const int lane = tid & 63, wid = tid >> 6;
    const int q = lane >> 4, cl = lane & 15;
    const int wm = (wid >> 1) * 64, wn = (wid & 1) * 64;

    // C tile -> LDS (stride 136: 16B-aligned rows)
#pragma unroll
    for (int i = 0; i < 4; i++)
#pragma unroll
        for (int j = 0; j < 4; j++) {
            const int col = wn + j * 16 + cl;
#pragma unroll
            for (int r = 0; r < 4; r++) {
                const int row = wm + i * 16 + q * 4 + r;
                SM[row * 136 + col] = f2bf(acc[i][j][r]);
            }
        }
    __syncthreads();

    if (z < 2) {
        ushort_t* ob = (z == 0) ? qb : kb;
        if (z == 1) {
#pragma unroll
            for (int t = 0; t < 4; t++) {
                const int g = t * 256 + tid, f = g >> 3, kbg = (g & 7) ^ (f & 7);
                gload16(projb + (size_t)f * 64 + kbg * 8, PS + (size_t)g * 8);
            }
        }
#pragma unroll
        for (int p = 0; p < 16; p++) {
            const int idx = p * 256 + tid;
            const int row = idx >> 5, c4 = idx & 31;
            ushort4 o = *(const ushort4*)&SM[row * 136 + c4 * 4];
            *(ushort4*)(ob + (size_t)(m0 + row) * DIMM + n0 + c4 * 4) = o;
        }
        if (z == 1) {
            const int bb = m0 >> 11;
            const int h0 = n0 >> 6;
            float mx[2] = {-3.0e38f, -3.0e38f};
#pragma unroll
            for (int half = 0; half < 2; half++) {
                __syncthreads();   // PS DMA drained; prior-half frag reads done
#pragma unroll
                for (int hh = 0; hh < 2; hh++) {
                    floatx4 a2[4][4];
#pragma unroll
                    for (int i = 0; i < 4; i++)
#pragma unroll
                        for (int j = 0; j < 4; j++) a2[i][j] = zero;
#pragma unroll
                    for (int ks = 0; ks < 2; ks++) {
                        bf16x8 af[4], bfr[4];
#pragma unroll
                        for (int i = 0; i < 4; i++)
                            af[i] = *(const bf16x8*)&SM[(wm + i * 16 + cl) * 136 + hh * 64 + (ks * 4 + q) * 8];
#pragma unroll
                        for (int j = 0; j < 4; j++)
                            bfr[j] = frag8(PS, wn + j * 16 + cl, ks * 4 + q);
#pragma unroll
                        for (int i = 0; i < 4; i++)
#pragma unroll
                            for (int j = 0; j < 4; j++)
                                a2[i][j] = __builtin_amdgcn_mfma_f32_16x16x32_bf16(
                                    af[i], bfr[j], a2[i][j], 0, 0, 0);
                    }
#pragma unroll
                    for (int i = 0; i < 4; i++)
#pragma unroll
                        for (int j = 0; j < 4; j++)
#pragma unroll
                            for (int r = 0; r < 4; r++) mx[hh] = fmaxf(mx[hh], a2[i][j][r]);
                }
                if (half == 0) {
                    __syncthreads();
#pragma unroll
                    for (int t = 0; t < 4; t++) {
                        const int g = t * 256 + tid, f = g >> 3, kbg = (g & 7) ^ (f & 7);
                        gload16(projb + (size_t)(128 + f) * 64 + kbg * 8, PS + (size_t)g * 8);
                    }
                }
            }
#pragma unroll
            for (int hh = 0; hh < 2; hh++) {
                __syncthreads();
                red[tid] = mx[hh];
                __syncthreads();
                for (int s = 128; s > 0; s >>= 1) {
                    if (tid < s) red[tid] = fmaxf(red[tid], red[tid + s]);
                    __syncthreads();
                }
                if (tid == 0) atomicMax(&mk_u[bb * NH + h0 + hh], enc_f(red[0]));
            }
        }
    } else {
        const int bb = m0 >> 11, nbase = m0 & 2047;
#pragma unroll
        for (int p = 0; p < 16; p++) {
            const int idx = p * 256 + tid;
            const int cl2 = idx >> 5, n4 = idx & 31;
            const int C = n0 + cl2;
            const int h = C >> 6, e = C & 63;
            union { ushort4 v4; unsigned short s[4]; } pk;
#pragma unroll
            for (int k = 0; k < 4; k++) pk.s[k] = SM[(n4 * 4 + k) * 136 + cl2];
            *(ushort4*)(vTb + (((size_t)(bb * NH + h) * 64 + e)) * NSEQ + nbase + n4 * 4) = pk.v4;
        }
    }
}

// ---------- output projection ----------
__global__ __launch_bounds__(256)
void gemm_out(const ushort_t* __restrict__ attnb, const ushort_t* __restrict__ Wto,
              float* __restrict__ out, const float* __restrict__ bias)
{
    __shared__ alignas(16) ushort_t As[8192];
    __shared__ alignas(16) ushort_t Bs[8192];
    const int tid = threadIdx.x;
    const int n0 = blockIdx.x * 128, m0 = blockIdx.y * 128;

    floatx4 zero = {0.f, 0.f, 0.f, 0.f};
    floatx4 acc[4][4];
#pragma unroll
    for (int i = 0; i < 4; i++)
#pragma unroll
        for (int j = 0; j < 4; j++) acc[i][j] = zero;

    mfma_mainloop(attnb + (size_t)m0 * DIMM, Wto + (size_t)n0 * DIMM, As, Bs,
                  DIMM, DIMM, DIMM, acc, tid);

    const int lane = tid & 63, wid = tid >> 6;
    const int q = lane >> 4, c = lane & 15;
    const int wm = (wid >> 1) * 64, wn = (wid & 1) * 64;
#pragma unroll
    for (int i = 0; i < 4; i++)
#pragma unroll
        for (int j = 0; j < 4; j++) {
            const int col = n0 + wn + j * 16 + c;
            const float bv = bias[col];
#pragma unroll
            for (int r = 0; r < 4; r++) {
                const int row = m0 + wm + i * 16 + q * 4 + r;
                out[(size_t)row * DIMM + col] = acc[i][j][r] + bv;
            }
        }
}

// =====================================================================
// featk: key features + exp -> kfb + Ksum + fused CTXT (m-tile == chunk).
// =====================================================================
__global__ __launch_bounds__(256)
void featk(const ushort_t* __restrict__ kb_, const ushort_t* __restrict__ projb,
           const unsigned* __restrict__ mk_u, const ushort_t* __restrict__ vTb,
           ushort_t* __restrict__ kfb, float* __restrict__ CTXT,
           float* __restrict__ Ksum)
{
    __shared__ alignas(16) ushort_t SM[24576];   // staging As(8192)+Bs(16384); reused
    __shared__ float dtmp[256];
    __shared__ float diag_l[128];
    __shared__ float colp[2][256];
    ushort_t* As = SM;
    ushort_t* Bs = SM + 8192;
    const int tid = threadIdx.x, lane = tid & 63, wid = tid >> 6;
    const int q = lane >> 4, cl = lane & 15;
    const int m0 = blockIdx.x * 128, h = blockIdx.y;
    const int bb = m0 >> 11, nloc = m0 & 2047;
    const int bh = bb * NH + h;
    const int cidx = nloc >> 7;
    const ushort_t* Aq = kb_ + (size_t)m0 * DIMM + h * 64;

    // diag[row] = sum(k^2)/16
    {
        const int row = tid >> 1, half = tid & 1;
        float s = 0.f;
        const ushort_t* p = Aq + (size_t)row * DIMM + half * 32;
#pragma unroll
        for (int d = 0; d < 32; d += 4) {
            ushort4 w = *(const ushort4*)(p + d);
            float a = bf2f(w.x), b2 = bf2f(w.y), c2 = bf2f(w.z), d2 = bf2f(w.w);
            s += a * a + b2 * b2 + c2 * c2 + d2 * d2;
        }
        dtmp[tid] = s;
    }
    __syncthreads();
    if (tid < 128) diag_l[tid] = (dtmp[2 * tid] + dtmp[2 * tid + 1]) * 0.0625f;

#pragma unroll
    for (int t = 0; t < 4; t++) {
        const int g = t * 256 + tid, r = g >> 3, kb = (g & 7) ^ (r & 7);
        gload16(Aq + (size_t)r * DIMM + kb * 8, As + (size_t)g * 8);
    }
#pragma unroll
    for (int t = 0; t < 8; t++) {
        const int g = t * 256 + tid, r = g >> 3, kb = (g & 7) ^ (r & 7);
        gload16(projb + (size_t)r * 64 + kb * 8, Bs + (size_t)g * 8);
    }
    __syncthreads();

    floatx4 zero = {0.f, 0.f, 0.f, 0.f};
    floatx4 acc[4][8];
#pragma unroll
    for (int i = 0; i < 4; i++)
#pragma unroll
        for (int j = 0; j < 8; j++) acc[i][j] = zero;
    const int wm = (wid >> 1) * 64, wn = (wid & 1) * 128;
#pragma unroll
    for (int ks = 0; ks < 2; ks++) {
        bf16x8 af[4], bfr[8];
#pragma unroll
        for (int i = 0; i < 4; i++) af[i] = frag8(As, wm + i * 16 + cl, ks * 4 + q);
#pragma unroll
        for (int j = 0; j < 8; j++) bfr[j] = frag8(Bs, wn + j * 16 + cl, ks * 4 + q);
#pragma unroll
        for (int i = 0; i < 4; i++)
#pragma unroll
            for (int j = 0; j < 8; j++)
                acc[i][j] = __builtin_amdgcn_mfma_f32_16x16x32_bf16(
                    af[i], bfr[j], acc[i][j], 0, 0, 0);
    }
    __syncthreads();   // frag ds_reads complete (SM reusable); diag visible

    const float mk = dec_f(mk_u[bh]);
#pragma unroll
    for (int i = 0; i < 4; i++)
#pragma unroll
        for (int r = 0; r < 4; r++) {
            const int row = wm + i * 16 + q * 4 + r;
            const float cc = diag_l[row] + mk;
#pragma unroll
            for (int j = 0; j < 8; j++)
                acc[i][j][r] = 0.0625f * (__expf(acc[i][j][r] - cc) + 1.0e-4f);
        }

    // column sums from registers (quad shuffles)
#pragma unroll
    for (int j = 0; j < 8; j++) {
        float s = 0.f;
#pragma unroll
        for (int i = 0; i < 4; i++)
            s += acc[i][j][0] + acc[i][j][1] + acc[i][j][2] + acc[i][j][3];
        s += __shfl_xor(s, 16);
        s += __shfl_xor(s, 32);
        if (q == 0) colp[wid >> 1][wn + j * 16 + cl] = s;
    }

    const size_t frow = (size_t)bh * NSEQ + nloc;
#pragma unroll
    for (int hf = 0; hf < 2; hf++) {
        __syncthreads();   // colp visible (hf=0); prior reads done (hf=1)
        if ((wid & 1) == hf) {
#pragma unroll
            for (int i = 0; i < 4; i++)
#pragma unroll
                for (int j = 0; j < 8; j++) {
                    const int col = j * 16 + cl;
#pragma unroll
                    for (int r = 0; r < 4; r++) {
                        const int row = wm + i * 16 + q * 4 + r;
                        SM[row * 132 + col] = f2bf(acc[i][j][r]);
                    }
                }
        }
        if (hf == 0) {
            Ksum[((size_t)bh * NCHK + cidx) * FF + tid] = colp[0][tid] + colp[1][tid];
        }
        __syncthreads();
#pragma unroll
        for (int p = 0; p < 16; p++) {
            const int idx = p * 256 + tid;
            const int row = idx >> 5, c4 = idx & 31;
            ushort4 o = *(const ushort4*)&SM[row * 132 + c4 * 4];
            *(ushort4*)(kfb + (frow + row) * FF + hf * 128 + c4 * 4) = o;
        }
    }

    // fused ctx: CTXT[bh][cidx][e][f] = sum_n vT[e][n] * kf[n][f]
    __syncthreads();   // all kfb-store reads of SM done before overwrite
    ushort_t* Vs = SM;
    ushort_t* T  = SM + 8192;
    const ushort_t* Vg = vTb + ((size_t)bh * 64) * NSEQ + nloc;
#pragma unroll
    for (int t = 0; t < 4; t++) {
        const int g = t * 256 + tid, r = g >> 4, kb = (g & 15) ^ (r & 15);
        gload16(Vg + (size_t)r * NSEQ + kb * 8, Vs + (size_t)g * 8);
    }

    const size_t cbase = ((size_t)bh * NCHK + cidx) * 64;
#pragma unroll
    for (int fq = 0; fq < 4; fq++) {
        if ((wid & 1) == (fq >> 1)) {
#pragma unroll
            for (int jj = 0; jj < 4; jj++) {
                const int j = (fq & 1) * 4 + jj;
#pragma unroll
                for (int i = 0; i < 4; i++)
#pragma unroll
                    for (int r = 0; r < 4; r++) {
                        const int n = wm + i * 16 + q * 4 + r;
                        T[(jj * 16 + cl) * 136 + n] = f2bf(acc[i][j][r]);
                    }
            }
        }
        __syncthreads();   // T ready; (fq=0) also drains Vs DMA
        floatx4 accc[4];
#pragma unroll
        for (int jj = 0; jj < 4; jj++) accc[jj] = zero;
#pragma unroll
        for (int kt = 0; kt < 4; kt++) {
            const bf16x8 av = fragS(Vs, wid * 16 + cl, kt * 4 + q);
#pragma unroll
            for (int jj = 0; jj < 4; jj++) {
                const bf16x8 bv = *(const bf16x8*)(T + (jj * 16 + cl) * 136 + (kt * 4 + q) * 8);
                accc[jj] = __builtin_amdgcn_mfma_f32_16x16x32_bf16(av, bv, accc[jj], 0, 0, 0);
            }
        }
#pragma unroll
        for (int jj = 0; jj < 4; jj++) {
            const int f = fq * 64 + jj * 16 + cl;
#pragma unroll
            for (int r = 0; r < 4; r++) {
                const int e = wid * 16 + q * 4 + r;
                CTXT[(cbase + e) * FF + f] = accc[jj][r];
            }
        }
        __syncthreads();
    }
}

// ---------- merged exclusive prefixes: blocks [0,1024) S-path, [1024,1040) Z-path ----------
__global__ void prefix_zs(float* __restrict__ Ksum, float* __restrict__ Zout,
                          const float* __restrict__ CTXT, ushort_t* __restrict__ ctxp,
                          float* __restrict__ Sout)
{
    const int b = blockIdx.x;
    if (b < 1024) {
        const int idx = b * 256 + threadIdx.x;
        const int bh = idx >> 14, ef = idx & 16383;
        const int e = ef >> 8, f = ef & 255;
        float run = 0.f;
#pragma unroll
        for (int c = 0; c < NCHK; c++) {
            const size_t o = (((size_t)bh * NCHK + c) * 64 + e) * FF + f;
            const float t = CTXT[o];
            ctxp[o] = f2bf(run);
            run += t;
        }
        Sout[((size_t)bh * FF + f) * 64 + e] = run;   // S[b,h,f,e]
    } else {
        const int idx = (b - 1024) * 256 + threadIdx.x;
        const int bh = idx >> 8, f = idx & 255;
        float run = 0.f;
#pragma unroll
        for (int c = 0; c < NCHK; c++) {
            const size_t o = ((size_t)(bh * NCHK + c)) * FF + f;
            const float t = Ksum[o];
            Ksum[o] = run;
            run += t;
        }
        Zout[(size_t)bh * FF + f] = run;
    }
}

// =====================================================================
// chunk output, full MFMA. qf recomputed in-block into QF (LDS, 4 frag8
// slices); qfb global surface eliminated.
// =====================================================================
__global__ __launch_bounds__(256)
void chunk_out_mfma(const ushort_t* __restrict__ qb_, const ushort_t* __restrict__ projb,
                    const ushort_t* __restrict__ kfb, const ushort_t* __restrict__ vTb,
                    const float* __restrict__ Zex, const ushort_t* __restrict__ ctxp,
                    ushort_t* __restrict__ attnb)
{
    __shared__ alignas(16) ushort_t QF[32768];   // 64 KB: qf, 4 slices of [128][8 gran]
    __shared__ alignas(16) ushort_t Sld[16384];  // 32 KB: proj staging / S / out-tile
    __shared__ alignas(16) ushort_t As[8192];    // 16 KB
    __shared__ alignas(16) ushort_t Bs[8192];    // 16 KB
    __shared__ float zeps[256];
    __shared__ float rows_part[2][128];
    __shared__ float denp[256];
    __shared__ float den_l[128];
    __shared__ float dtmp[256];
    __shared__ float diag_l[128];
    __shared__ float mx2[2][128];

    const int tid = threadIdx.x, lane = tid & 63, wid = tid >> 6;
    const int q = lane >> 4, cl = lane & 15;
    const int bh = blockIdx.x >> 4, c = blockIdx.x & 15;
    const int bb = bh >> 3, h = bh & 7;
    const int n0 = c * CHK;
    const ushort_t* Kf = kfb + ((size_t)bh * NSEQ + n0) * FF;
    const ushort_t* Aq = qb_ + ((size_t)(bb * NSEQ + n0)) * DIMM + h * 64;

    zeps[tid] = Zex[((size_t)bh * NCHK + c) * FF + tid] + 1.0e-6f;

    // ---- phase 0: recompute qf chunk into QF ----
    {
        const int row = tid >> 1, half = tid & 1;
        float s = 0.f;
        const ushort_t* p = Aq + (size_t)row * DIMM + half * 32;
#pragma unroll
        for (int d = 0; d < 32; d += 4) {
            ushort4 w = *(const ushort4*)(p + d);
            float a = bf2f(w.x), b2 = bf2f(w.y), c2 = bf2f(w.z), d2 = bf2f(w.w);
            s += a * a + b2 * b2 + c2 * c2 + d2 * d2;
        }
        dtmp[tid] = s;
    }
    __syncthreads();
    if (tid < 128) diag_l[tid] = (dtmp[2 * tid] + dtmp[2 * tid + 1]) * 0.0625f;

#pragma unroll
    for (int t = 0; t < 4; t++) {
        const int g = t * 256 + tid, r = g >> 3, kb = (g & 7) ^ (r & 7);
        gload16(Aq + (size_t)r * DIMM + kb * 8, As + (size_t)g * 8);
    }
#pragma unroll
    for (int t = 0; t < 8; t++) {
        const int g = t * 256 + tid, r = g >> 3, kb = (g & 7) ^ (r & 7);
        gload16(projb + (size_t)r * 64 + kb * 8, Sld + (size_t)g * 8);
    }
    __syncthreads();

    floatx4 zero = {0.f, 0.f, 0.f, 0.f};
    {
        floatx4 accq[4][8];
#pragma unroll
        for (int i = 0; i < 4; i++)
#pragma unroll
            for (int j = 0; j < 8; j++) accq[i][j] = zero;
        const int wmF = (wid >> 1) * 64, wnF = (wid & 1) * 128;
#pragma unroll
        for (int ks = 0; ks < 2; ks++) {
            bf16x8 af[4], bfr[8];
#pragma unroll
            for (int i = 0; i < 4; i++) af[i] = frag8(As, wmF + i * 16 + cl, ks * 4 + q);
#pragma unroll
            for (int j = 0; j < 8; j++) bfr[j] = frag8(Sld, wnF + j * 16 + cl, ks * 4 + q);
#pragma unroll
            for (int i = 0; i < 4; i++)
#pragma unroll
                for (int j = 0; j < 8; j++)
                    accq[i][j] = __builtin_amdgcn_mfma_f32_16x16x32_bf16(
                        af[i], bfr[j], accq[i][j], 0, 0, 0);
        }
        // per-row max
#pragma unroll
        for (int i = 0; i < 4; i++)
#pragma unroll
            for (int r = 0; r < 4; r++) {
                const int row = wmF + i * 16 + q * 4 + r;
                float mx = -3.0e38f;
#pragma unroll
                for (int j = 0; j < 8; j++) mx = fmaxf(mx, accq[i][j][r]);
                mx = fmaxf(mx, __shfl_xor(mx, 1)); mx = fmaxf(mx, __shfl_xor(mx, 2));
                mx = fmaxf(mx, __shfl_xor(mx, 4)); mx = fmaxf(mx, __shfl_xor(mx, 8));
                if (cl == 0) mx2[wid & 1][row] = mx;
            }
        __syncthreads();
        // exp + write to QF slices (frag8 layout per 64-f slice)
#pragma unroll
        for (int i = 0; i < 4; i++)
#pragma unroll
            for (int r = 0; r < 4; r++) {
                const int row = wmF + i * 16 + q * 4 + r;
                const float cc = diag_l[row] + fmaxf(mx2[0][row], mx2[1][row]);
#pragma unroll
                for (int j = 0; j < 8; j++) {
                    const int col = wnF + j * 16 + cl;
                    const float v = 0.0625f * (__expf(accq[i][j][r] - cc) + 1.0e-4f);
                    const int s = col >> 6, fp = col & 63;
                    QF[s * 8192 + (row * 8 + ((fp >> 3) ^ (row & 7))) * 8 + (fp & 7)] = f2bf(v);
                }
            }
    }
    __syncthreads();   // QF complete (and Sld/As frag reads done)

    // ---- stage 1: S = Q @ Kf^T (K=256); Q from QF, Kf streamed ----
    floatx4 acc1[4][4];
#pragma unroll
    for (int i = 0; i < 4; i++)
#pragma unroll
        for (int j = 0; j < 4; j++) acc1[i][j] = zero;
    const int wm = (wid >> 1) * 64, wn = (wid & 1) * 64;
    for (int k0 = 0; k0 < FF; k0 += 64) {
#pragma unroll
        for (int t = 0; t < 4; t++) {
            const int g = t * 256 + tid, r = g >> 3, kb = (g & 7) ^ (r & 7);
            gload16(Kf + (size_t)r * FF + k0 + kb * 8, Bs + (size_t)g * 8);
        }
        __syncthreads();
        const ushort_t* QFs = QF + (k0 >> 6) * 8192;
#pragma unroll
        for (int ks = 0; ks < 2; ks++) {
            bf16x8 af[4], bfr[4];
#pragma unroll
            for (int i = 0; i < 4; i++) {
                af[i]  = frag8(QFs, wm + i * 16 + cl, ks * 4 + q);
                bfr[i] = frag8(Bs, wn + i * 16 + cl, ks * 4 + q);
            }
#pragma unroll
            for (int i = 0; i < 4; i++)
#pragma unroll
                for (int j = 0; j < 4; j++)
                    acc1[i][j] = __builtin_amdgcn_mfma_f32_16x16x32_bf16(
                        af[i], bfr[j], acc1[i][j], 0, 0, 0);
        }
        __syncthreads();
    }
    // ---- causal mask + rowsum(fp32) + S -> Sld (bf16, swizzled granules) ----
#pragma unroll
    for (int i = 0; i < 4; i++)
#pragma unroll
        for (int r = 0; r < 4; r++) {
            const int row = wm + i * 16 + q * 4 + r;
            float part = 0.f;
#pragma unroll
            for (int j = 0; j < 4; j++) {
                const int col = wn + j * 16 + cl;
                const float v = (col <= row) ? acc1[i][j][r] : 0.f;
                part += v;
                Sld[(row * 16 + ((col >> 3) ^ (row & 15))) * 8 + (col & 7)] = f2bf(v);
            }
            part += __shfl_xor(part, 1); part += __shfl_xor(part, 2);
            part += __shfl_xor(part, 4); part += __shfl_xor(part, 8);
            if (cl == 0) rows_part[wid & 1][row] = part;
        }
    __syncthreads();

    // ---- stage 3: acc2[e][row] += vT (x) S  (K = 128 seq) ----
    floatx4 acc2[4][2];
#pragma unroll
    for (int i = 0; i < 4; i++)
#pragma unroll
        for (int j = 0; j < 2; j++) acc2[i][j] = zero;
    const ushort_t* Vt = vTb + ((size_t)bh * 64) * NSEQ + n0;
    for (int k0 = 0; k0 < CHK; k0 += 64) {
#pragma unroll
        for (int t = 0; t < 2; t++) {
            const int g = t * 256 + tid, r = g >> 3, kb = (g & 7) ^ (r & 7);
            gload16(Vt + (size_t)r * NSEQ + k0 + kb * 8, As + (size_t)g * 8);
        }
        __syncthreads();
#pragma unroll
        for (int ks = 0; ks < 2; ks++) {
            bf16x8 af[4], bfr[2];
            const int kbS = (k0 >> 3) + ks * 4 + q;
#pragma unroll
            for (int i = 0; i < 4; i++) af[i] = frag8(As, i * 16 + cl, ks * 4 + q);
#pragma unroll
            for (int j = 0; j < 2; j++) bfr[j] = fragS(Sld, wid * 32 + j * 16 + cl, kbS);
#pragma unroll
            for (int i = 0; i < 4; i++)
#pragma unroll
                for (int j = 0; j < 2; j++)
                    acc2[i][j] = __builtin_amdgcn_mfma_f32_16x16x32_bf16(
                        af[i], bfr[j], acc2[i][j], 0, 0, 0);
        }
        __syncthreads();
    }

    // ---- stage 4: acc2 += ctxp (x) Q  (K = 256 features); Q/den from QF ----
    const ushort_t* Cp = ctxp + ((size_t)bh * NCHK + c) * 64 * FF;
    float dacc = 0.f;
    const int drow = tid & 127, dhalf = tid >> 7;
    for (int k0 = 0; k0 < FF; k0 += 64) {
#pragma unroll
        for (int t = 0; t < 2; t++) {
            const int g = t * 256 + tid, r = g >> 3, kb = (g & 7) ^ (r & 7);
            gload16(Cp + (size_t)r * FF + k0 + kb * 8, As + (size_t)g * 8);
        }
        __syncthreads();
        const ushort_t* QFs = QF + (k0 >> 6) * 8192;
#pragma unroll
        for (int ks = 0; ks < 2; ks++) {
            bf16x8 af[4], bfr[2];
#pragma unroll
            for (int i = 0; i < 4; i++) af[i] = frag8(As, i * 16 + cl, ks * 4 + q);
#pragma unroll
            for (int j = 0; j < 2; j++) bfr[j] = frag8(QFs, wid * 32 + j * 16 + cl, ks * 4 + q);
#pragma unroll
            for (int i = 0; i < 4; i++)
#pragma unroll
                for (int j = 0; j < 2; j++)
                    acc2[i][j] = __builtin_amdgcn_mfma_f32_16x16x32_bf16(
                        af[i], bfr[j], acc2[i][j], 0, 0, 0);
        }
        // den partial: this thread's row, its 32-feature half of this k-step
#pragma unroll
        for (int gi = 0; gi < 4; gi++) {
            const int kb = dhalf * 4 + gi;
            const ushort_t* gp = QFs + ((size_t)drow * 8 + (kb ^ (drow & 7))) * 8;
            const int kbase = k0 + kb * 8;
#pragma unroll
            for (int e2 = 0; e2 < 8; e2++)
                dacc = fmaf(bf2f(gp[e2]), zeps[kbase + e2], dacc);
        }
        __syncthreads();
    }
    denp[tid] = dacc;
    __syncthreads();
    if (tid < 128)
        den_l[tid] = rows_part[0][tid] + rows_part[1][tid] + denp[tid] + denp[tid + 128];
    __syncthreads();

    // ---- epilogue: divide, transpose via LDS, coalesced bf16 store ----
#pragma unroll
    for (int j = 0; j < 2; j++) {
        const int row = wid * 32 + j * 16 + cl;
        const float dinv = 1.0f / den_l[row];
#pragma unroll
        for (int i = 0; i < 4; i++)
#pragma unroll
            for (int r = 0; r < 4; r++) {
                const int e = i * 16 + q * 4 + r;
                Sld[row * 68 + e] = f2bf(acc2[i][j][r] * dinv);
            }
    }
    __syncthreads();
#pragma unroll
    for (int p = 0; p < 8; p++) {
        const int idx = p * 256 + tid;
        const int row = idx >> 4, e4 = idx & 15;
        ushort4 o = *(const ushort4*)&Sld[row * 68 + e4 * 4];
        *(ushort4*)(attnb + ((size_t)(bb * NSEQ + n0 + row)) * DIMM + h * 64 + e4 * 4) = o;
    }
}

extern "C" void kernel_launch(void* const* d_in, const int* in_sizes, int n_in,
                              void* d_out, int out_size, void* d_ws, size_t ws_size,
                              hipStream_t stream)
{
    (void)in_sizes; (void)n_in; (void)out_size; (void)ws_size;
    const float* x    = (const float*)d_in[0];
    const float* proj = (const float*)d_in[1];
    const float* Wq   = (const float*)d_in[2];
    const float* Wk   = (const float*)d_in[3];
    const float* Wv   = (const float*)d_in[4];
    const float* Wo   = (const float*)d_in[5];
    const float* bo   = (const float*)d_in[6];
    float* out = (float*)d_out;

    // ---- workspace carve (~61 MB) ----
    char* W = (char*)d_ws;
    float*    CTXT = (float*)W;              W += (size_t)16777216;   // [bh][c][e][f] fp32
    ushort_t* kfb  = (ushort_t*)W;           W += (size_t)16777216;   // [bh][n][f] bf16
    ushort_t* ctxp = (ushort_t*)W;           W += (size_t)8388608;    // [bh][c][e][f] bf16
    ushort_t* qb   = (ushort_t*)W;           W += (size_t)4194304;    // [n][dim] bf16 (live into chunk_out)
    ushort_t* kb   = (ushort_t*)W;           W += (size_t)4194304;
    ushort_t* xb   = (ushort_t*)W;           W += (size_t)4194304;    // reused as attnb
    ushort_t* vTb  = (ushort_t*)W;           W += (size_t)4194304;    // [bh][e][n]
    ushort_t* Wtq  = (ushort_t*)W;           W += (size_t)524288;
    ushort_t* Wtk  = (ushort_t*)W;           W += (size_t)524288;
    ushort_t* Wtv  = (ushort_t*)W;           W += (size_t)524288;
    ushort_t* Wto  = (ushort_t*)W;           W += (size_t)524288;
    ushort_t* projb = (ushort_t*)W;          W += (size_t)32768;
    float*    Ksum = (float*)W;              W += (size_t)262144;     // [bh][c][f]
    unsigned* mk_u = (unsigned*)W;           W += (size_t)256;

    ushort_t* attnb = xb;          // xb dead after gemm_qkv

    float* Zout = out + (size_t)4096 * 512;
    float* Sout = Zout + (size_t)NBH * FF;

    hipLaunchKernelGGL(prep, dim3(3089), dim3(256), 0, stream,
                       x, proj, Wq, Wk, Wv, Wo, xb, projb, Wtq, Wtk, Wtv, Wto, mk_u);
    hipLaunchKernelGGL(gemm_qkv, dim3(4, 32, 3), dim3(256), 0, stream,
                       xb, Wtq, Wtk, Wtv, projb, qb, kb, vTb, mk_u);
    hipLaunchKernelGGL(featk, dim3(32, 8), dim3(256), 0, stream,
                       kb, projb, mk_u, vTb, kfb, CTXT, Ksum);
    hipLaunchKernelGGL(prefix_zs, dim3(1040), dim3(256), 0, stream,
                       Ksum, Zout, CTXT, ctxp, Sout);
    hipLaunchKernelGGL(chunk_out_mfma, dim3(256), dim3(256), 0, stream,
                       qb, projb, kfb, vTb, Ksum, ctxp, attnb);
    hipLaunchKernelGGL(gemm_out, dim3(4, 32), dim3(256), 0, stream, attnb, Wto, out, bo);
}